// Round 2
// baseline (111.677 us; speedup 1.0000x reference)
//
#include <hip/hip_runtime.h>

// Problem constants
#define HEADS 8
#define CH    64      // per-head dim == x channels
#define HW    4096
#define MTOK  256     // z tokens
#define DIMZ  256     // z feature dim
#define INNER 512     // heads*CH
#define LROWS 512     // HW/8 distinct query rows per head

// ---------------------------------------------------------------------------
// Kernel A: klin = z@Wk + bk, vlin = z@Wv + bv
// z: (8*256, 256) row-major; W: (256, 512); out: (2048, 512)
// Tiles 64x64, BK=32, 256 threads, 4x4 acc/thread.
// ---------------------------------------------------------------------------
__global__ __launch_bounds__(256) void kv_gemm(
    const float* __restrict__ z,
    const float* __restrict__ Wk, const float* __restrict__ bk,
    const float* __restrict__ Wv, const float* __restrict__ bv,
    float* __restrict__ klin, float* __restrict__ vlin) {
  __shared__ __align__(16) float As[32][68];
  __shared__ __align__(16) float Bs[32][68];
  const int t  = threadIdx.x;
  const int m0 = blockIdx.x * 64;           // 0..31 -> rows of 2048
  const int bn = blockIdx.y;                // 0..15; 0..7 K, 8..15 V
  const bool isK = bn < 8;
  const int n0 = (bn & 7) * 64;
  const float* __restrict__ W    = isK ? Wk : Wv;
  const float* __restrict__ bias = isK ? bk : bv;
  float* __restrict__ out        = isK ? klin : vlin;
  const int tx = t & 15, ty = t >> 4;
  float acc[4][4] = {};
  for (int k0 = 0; k0 < DIMZ; k0 += 32) {
#pragma unroll
    for (int j = 0; j < 8; ++j) {
      int idx = t + j * 256;                 // 2048 = 64 rows x 32 k
      As[idx & 31][idx >> 5] = z[(size_t)(m0 + (idx >> 5)) * DIMZ + k0 + (idx & 31)];
    }
#pragma unroll
    for (int j = 0; j < 8; ++j) {
      int idx = t + j * 256;                 // 2048 = 32 k x 64 cols
      Bs[idx >> 6][idx & 63] = W[(size_t)(k0 + (idx >> 6)) * INNER + n0 + (idx & 63)];
    }
    __syncthreads();
#pragma unroll
    for (int kk = 0; kk < 32; ++kk) {
      float a[4]; *(float4*)a = *(const float4*)&As[kk][ty * 4];
      float b[4]; *(float4*)b = *(const float4*)&Bs[kk][tx * 4];
#pragma unroll
      for (int i = 0; i < 4; ++i)
#pragma unroll
        for (int jj = 0; jj < 4; ++jj) acc[i][jj] += a[i] * b[jj];
    }
    __syncthreads();
  }
  float bv4[4]; *(float4*)bv4 = *(const float4*)&bias[n0 + tx * 4];
#pragma unroll
  for (int i = 0; i < 4; ++i) {
    int row = m0 + ty * 4 + i;
    float4 o = make_float4(acc[i][0] + bv4[0], acc[i][1] + bv4[1],
                           acc[i][2] + bv4[2], acc[i][3] + bv4[3]);
    *(float4*)&out[(size_t)row * INNER + n0 + tx * 4] = o;
  }
}

// ---------------------------------------------------------------------------
// Kernel B: per (b, head, 32-row L-tile): S = Q K^T * scale, softmax rows,
// O = P V.  Q rows contiguous in x; K/V head slabs contiguous in klin/vlin.
// Output written in (b, L, heads*CH) layout for the projection GEMM.
// Block = 256 threads; thread t owns row l = t>>3 (s = t&7 sub-lane).
// ---------------------------------------------------------------------------
__global__ __launch_bounds__(256) void attn_kernel(
    const float* __restrict__ x,
    const float* __restrict__ klin, const float* __restrict__ vlin,
    float* __restrict__ out2) {
  __shared__ __align__(16) float Sq[32][68];
  __shared__ __align__(16) float KV[64][68];
  __shared__ float S[32][257];
  const int t  = threadIdx.x;
  const int blk = blockIdx.x;               // b*128 + hh*16 + lt
  const int lt = blk & 15;
  const int hh = (blk >> 4) & 7;
  const int b  = blk >> 7;
  const float* Qg = x    + (size_t)b * (HW * CH) + (size_t)hh * (LROWS * CH) + (size_t)lt * 32 * CH;
  const float* Kg = klin + (size_t)b * (MTOK * INNER) + (size_t)hh * (MTOK * CH);
  const float* Vg = vlin + (size_t)b * (MTOK * INNER) + (size_t)hh * (MTOK * CH);
#pragma unroll
  for (int j = 0; j < 8; ++j) {
    int idx = t + j * 256;                   // 32x64 Q tile = 2048
    Sq[idx >> 6][idx & 63] = Qg[idx];
  }
  const int l = t >> 3, s = t & 7;
  float sreg[32];
  // ---- S = Q K^T, K in 4 chunks of 64 rows ----
  for (int ch = 0; ch < 4; ++ch) {
    __syncthreads();
#pragma unroll
    for (int j = 0; j < 16; ++j) {           // 64x64 chunk = 4096 elements
      int idx = t + j * 256;
      KV[idx >> 6][idx & 63] = Kg[ch * 4096 + idx];
    }
    __syncthreads();
    float acc8[8] = {};
#pragma unroll 4
    for (int c4 = 0; c4 < 16; ++c4) {
      float q[4]; *(float4*)q = *(const float4*)&Sq[l][c4 * 4];
#pragma unroll
      for (int i = 0; i < 8; ++i) {          // this thread's keys: s + 8*i
        float k[4]; *(float4*)k = *(const float4*)&KV[s + 8 * i][c4 * 4];
        acc8[i] += q[0] * k[0] + q[1] * k[1] + q[2] * k[2] + q[3] * k[3];
      }
    }
#pragma unroll
    for (int i = 0; i < 8; ++i) sreg[ch * 8 + i] = acc8[i] * 0.125f;  // 1/sqrt(64)
  }
  // ---- softmax over 256 keys, distributed over the 8 sub-lanes of row l ----
  float mx = sreg[0];
#pragma unroll
  for (int i = 1; i < 32; ++i) mx = fmaxf(mx, sreg[i]);
  for (int off = 1; off < 8; off <<= 1) mx = fmaxf(mx, __shfl_xor(mx, off, 8));
  float sum = 0.f;
#pragma unroll
  for (int i = 0; i < 32; ++i) { float e = __expf(sreg[i] - mx); sreg[i] = e; sum += e; }
  for (int off = 1; off < 8; off <<= 1) sum += __shfl_xor(sum, off, 8);
  const float inv = 1.f / sum;
#pragma unroll
  for (int ch = 0; ch < 4; ++ch)
#pragma unroll
    for (int i = 0; i < 8; ++i)
      S[l][ch * 64 + s + 8 * i] = sreg[ch * 8 + i] * inv;
  // ---- O = P V, V in 4 chunks of 64 rows; thread owns cols s*8..s*8+7 ----
  float acc2[8] = {};
  for (int ch = 0; ch < 4; ++ch) {
    __syncthreads();                          // S visible / KV free
#pragma unroll
    for (int j = 0; j < 16; ++j) {           // 64x64 chunk = 4096 elements
      int idx = t + j * 256;
      KV[idx >> 6][idx & 63] = Vg[ch * 4096 + idx];
    }
    __syncthreads();
#pragma unroll 8
    for (int mm = 0; mm < 64; ++mm) {
      float p = S[l][ch * 64 + mm];
      float va[4]; *(float4*)va = *(const float4*)&KV[mm][s * 8];
      float vb[4]; *(float4*)vb = *(const float4*)&KV[mm][s * 8 + 4];
      acc2[0] += p * va[0]; acc2[1] += p * va[1]; acc2[2] += p * va[2]; acc2[3] += p * va[3];
      acc2[4] += p * vb[0]; acc2[5] += p * vb[1]; acc2[6] += p * vb[2]; acc2[7] += p * vb[3];
    }
  }
  float* o = out2 + (size_t)b * (LROWS * INNER) + (size_t)(lt * 32 + l) * INNER + hh * CH + s * 8;
  *(float4*)&o[0] = *(float4*)&acc2[0];
  *(float4*)&o[4] = *(float4*)&acc2[4];
}

// ---------------------------------------------------------------------------
// Kernel C: O = out2 @ Wo + bo  (4096x512x64), then y row (b, L*8+r) =
// x row + O row (broadcast 8x) — the final residual output.
// ---------------------------------------------------------------------------
__global__ __launch_bounds__(256) void proj_kernel(
    const float* __restrict__ out2,
    const float* __restrict__ Wo, const float* __restrict__ bo,
    const float* __restrict__ x, float* __restrict__ y) {
  __shared__ __align__(16) float As[32][68];
  __shared__ __align__(16) float Bs[32][68];
  const int t  = threadIdx.x;
  const int m0 = blockIdx.x * 64;            // 64 blocks over M=4096
  const int tx = t & 15, ty = t >> 4;
  float acc[4][4] = {};
  for (int k0 = 0; k0 < INNER; k0 += 32) {
#pragma unroll
    for (int j = 0; j < 8; ++j) {
      int idx = t + j * 256;
      As[idx & 31][idx >> 5] = out2[(size_t)(m0 + (idx >> 5)) * INNER + k0 + (idx & 31)];
    }
#pragma unroll
    for (int j = 0; j < 8; ++j) {
      int idx = t + j * 256;
      Bs[idx >> 6][idx & 63] = Wo[(size_t)(k0 + (idx >> 6)) * CH + (idx & 63)];
    }
    __syncthreads();
#pragma unroll
    for (int kk = 0; kk < 32; ++kk) {
      float a[4]; *(float4*)a = *(const float4*)&As[kk][ty * 4];
      float b[4]; *(float4*)b = *(const float4*)&Bs[kk][tx * 4];
#pragma unroll
      for (int i = 0; i < 4; ++i)
#pragma unroll
        for (int jj = 0; jj < 4; ++jj) acc[i][jj] += a[i] * b[jj];
    }
    __syncthreads();
  }
  float bo4[4]; *(float4*)bo4 = *(const float4*)&bo[tx * 4];
#pragma unroll
  for (int i = 0; i < 4; ++i) {
    int m = m0 + ty * 4 + i;
    int bb = m >> 9, L = m & 511;
    float4 val = make_float4(acc[i][0] + bo4[0], acc[i][1] + bo4[1],
                             acc[i][2] + bo4[2], acc[i][3] + bo4[3]);
    const float* xr = x + (size_t)bb * (HW * CH) + (size_t)L * 8 * CH + tx * 4;
    float*       yr = y + (size_t)bb * (HW * CH) + (size_t)L * 8 * CH + tx * 4;
#pragma unroll
    for (int r = 0; r < 8; ++r) {
      float xv[4]; *(float4*)xv = *(const float4*)&xr[r * CH];
      float4 o = make_float4(val.x + xv[0], val.y + xv[1], val.z + xv[2], val.w + xv[3]);
      *(float4*)&yr[r * CH] = o;
    }
  }
}

extern "C" void kernel_launch(void* const* d_in, const int* in_sizes, int n_in,
                              void* d_out, int out_size, void* d_ws, size_t ws_size,
                              hipStream_t stream) {
  const float* x  = (const float*)d_in[0];
  const float* z  = (const float*)d_in[1];
  const float* Wk = (const float*)d_in[2];
  const float* bk = (const float*)d_in[3];
  const float* Wv = (const float*)d_in[4];
  const float* bv = (const float*)d_in[5];
  const float* Wo = (const float*)d_in[6];
  const float* bo = (const float*)d_in[7];
  float* y = (float*)d_out;

  // ws: klin (8*256*512) | vlin (8*256*512) | out2 (8*512*512)  = 16 MB fp32
  float* klin = (float*)d_ws;
  float* vlin = klin + 8 * MTOK * INNER;
  float* out2 = vlin + 8 * MTOK * INNER;

  dim3 gA(32, 16);
  kv_gemm<<<gA, 256, 0, stream>>>(z, Wk, bk, Wv, bv, klin, vlin);
  attn_kernel<<<1024, 256, 0, stream>>>(x, klin, vlin, out2);
  proj_kernel<<<64, 256, 0, stream>>>(out2, Wo, bo, x, y);
}

// Round 4
// 91.200 us; speedup vs baseline: 1.2245x; 1.2245x over previous
//
#include <hip/hip_runtime.h>

#define HEADS 8
#define CH    64      // per-head dim == x channel dim
#define HW    4096
#define MTOK  256     // z tokens
#define DIMZ  256     // z feature dim
#define INNER 512     // heads*CH
#define LROWS 512     // HW/8 distinct query rows per head

typedef __attribute__((ext_vector_type(8))) __bf16 bf16x8;
typedef __attribute__((ext_vector_type(4))) float  f32x4;

// round-to-nearest-even f32 -> bf16 bits
__device__ __forceinline__ unsigned f2bf(float f) {
  unsigned u = __float_as_uint(f);
  return (u + 0x7fffu + ((u >> 16) & 1u)) >> 16;
}

__device__ __forceinline__ bf16x8 ld_bf8(const unsigned short* p) {
  uint4 v = *(const uint4*)p;
  return __builtin_bit_cast(bf16x8, v);
}

// ---------------------------------------------------------------------------
// Kernel A: klin = bf16(z@Wk + bk), plain row-major (2048, 512).
//           vt   = bf16(z@Wv + bv) in [b][h][c][key'] with key' = cb*32 + t,
//                  where h = token>>5 (true head = token block), t = token&31,
//                  cb = feature>>6, c = feature&63.
// fp32 compute, 64x64 tiles, BK=32, 256 threads, 4x4 acc/thread.
// ---------------------------------------------------------------------------
__global__ __launch_bounds__(256) void kv_gemm(
    const float* __restrict__ z,
    const float* __restrict__ Wk, const float* __restrict__ bk,
    const float* __restrict__ Wv, const float* __restrict__ bv,
    unsigned short* __restrict__ klin, unsigned short* __restrict__ vt) {
  __shared__ __align__(16) float As[32][68];
  __shared__ __align__(16) float Bs[32][68];
  const int t  = threadIdx.x;
  const int m0 = blockIdx.x * 64;           // token rows (b*256 + mtok)
  const int bn = blockIdx.y;                // 0..15; 0..7 K, 8..15 V
  const bool isK = bn < 8;
  const int cb = bn & 7;                    // 64-wide column block of INNER
  const int n0 = cb * 64;
  const float* __restrict__ W    = isK ? Wk : Wv;
  const float* __restrict__ bias = isK ? bk : bv;
  const int tx = t & 15, ty = t >> 4;
  float acc[4][4] = {};
  for (int k0 = 0; k0 < DIMZ; k0 += 32) {
#pragma unroll
    for (int j = 0; j < 8; ++j) {
      int idx = t + j * 256;                 // 64 rows x 32 k
      As[idx & 31][idx >> 5] = z[(size_t)(m0 + (idx >> 5)) * DIMZ + k0 + (idx & 31)];
    }
#pragma unroll
    for (int j = 0; j < 8; ++j) {
      int idx = t + j * 256;                 // 32 k x 64 cols
      Bs[idx >> 6][idx & 63] = W[(size_t)(k0 + (idx >> 6)) * INNER + n0 + (idx & 63)];
    }
    __syncthreads();
#pragma unroll
    for (int kk = 0; kk < 32; ++kk) {
      float a[4]; *(float4*)a = *(const float4*)&As[kk][ty * 4];
      float b[4]; *(float4*)b = *(const float4*)&Bs[kk][tx * 4];
#pragma unroll
      for (int i = 0; i < 4; ++i)
#pragma unroll
        for (int jj = 0; jj < 4; ++jj) acc[i][jj] += a[i] * b[jj];
    }
    __syncthreads();
  }
  float bv4[4]; *(float4*)bv4 = *(const float4*)&bias[n0 + tx * 4];
  if (isK) {
    // plain row-major bf16 (2048 x 512)
#pragma unroll
    for (int i = 0; i < 4; ++i) {
      int row = m0 + ty * 4 + i;
      uint2 w;
      w.x = f2bf(acc[i][0] + bv4[0]) | (f2bf(acc[i][1] + bv4[1]) << 16);
      w.y = f2bf(acc[i][2] + bv4[2]) | (f2bf(acc[i][3] + bv4[3]) << 16);
      *(uint2*)(klin + (size_t)row * INNER + n0 + tx * 4) = w;
    }
  } else {
    // vt[b][h][c][cb*32 + t] ; pack 4 consecutive tokens t0..t0+3
    int bb = m0 >> 8;
    int mt0 = (m0 & 255) + ty * 4;           // token-in-batch base (mult of 4)
    int h  = mt0 >> 5;                       // true head
    int t0 = mt0 & 31;
#pragma unroll
    for (int jj = 0; jj < 4; ++jj) {
      int cc = tx * 4 + jj;                  // channel within head
      uint2 w;
      w.x = f2bf(acc[0][jj] + bv4[jj]) | (f2bf(acc[1][jj] + bv4[jj]) << 16);
      w.y = f2bf(acc[2][jj] + bv4[jj]) | (f2bf(acc[3][jj] + bv4[jj]) << 16);
      *(uint2*)(vt + ((size_t)((bb * HEADS + h) * CH + cc)) * MTOK + cb * 32 + t0) = w;
    }
  }
}

// ---------------------------------------------------------------------------
// Kernel B (MFMA attention): one wave per (b, h, 32-query tile).
// Keys enumerated as key' = cb*32 + t (consistent permutation on K and V):
//   K[key'][c]  = klin[b*256 + h*32 + t][cb*64 + c]   (row-major linout)
//   V^T[c][key'] = vt slab (written by kv_gemm)
//  S^T = mfma(K, Q) -> lane-local softmax (2 shfl_xor) -> P bf16 in LDS
//  O^T = mfma(V^T, P) -> deferred 1/rowsum -> float4 stores to out2
// ---------------------------------------------------------------------------
__global__ __launch_bounds__(64) void attn_mfma(
    const float* __restrict__ x,
    const unsigned short* __restrict__ kbf,
    const unsigned short* __restrict__ vtbf,
    float* __restrict__ out2) {
  __shared__ unsigned short Psh[32 * 256];   // 16 KB
  char* Pb = (char*)Psh;
  const int t = threadIdx.x;
  const int c = t & 15, g = t >> 4;
  const int bid = blockIdx.x;                // b*128 + hh*16 + lt
  const int lt = bid & 15, hh = (bid >> 4) & 7, b = bid >> 7;
  const int qbase = lt * 32;
  const float* xs = x + (size_t)b * (HW * CH) + (size_t)hh * (LROWS * CH);
  const unsigned short* Kg = kbf + ((size_t)b * MTOK + hh * 32) * INNER; // [32 tok][512]
  const unsigned short* Vg = vtbf + (size_t)(b * HEADS + hh) * (CH * MTOK);

  // ---- Q fragments (B-operand), scale 1/8 folded in (exact pow2) ----
  bf16x8 qfr[2][2];
#pragma unroll
  for (int qf = 0; qf < 2; ++qf)
#pragma unroll
    for (int ks = 0; ks < 2; ++ks) {
      const float* qp = xs + (size_t)(qbase + 16 * qf + c) * CH + 32 * ks + 8 * g;
      float4 f0 = *(const float4*)qp;
      float4 f1 = *(const float4*)(qp + 4);
      uint4 u;
      u.x = f2bf(f0.x * 0.125f) | (f2bf(f0.y * 0.125f) << 16);
      u.y = f2bf(f0.z * 0.125f) | (f2bf(f0.w * 0.125f) << 16);
      u.z = f2bf(f1.x * 0.125f) | (f2bf(f1.y * 0.125f) << 16);
      u.w = f2bf(f1.z * 0.125f) | (f2bf(f1.w * 0.125f) << 16);
      qfr[qf][ks] = __builtin_bit_cast(bf16x8, u);
    }

  // ---- S^T = K · Q^T : acc[qf][kf]; key' = 16*kf + c_row ----
  // K row for key' = 16kf + r: token (kf&1)*16 + r, feat (kf>>1)*64 + chan
  f32x4 acc[2][16];
#pragma unroll
  for (int qf = 0; qf < 2; ++qf)
#pragma unroll
    for (int kf = 0; kf < 16; ++kf) acc[qf][kf] = (f32x4)0.f;
#pragma unroll
  for (int kf = 0; kf < 16; ++kf) {
    const unsigned short* kp =
        Kg + (size_t)((kf & 1) * 16 + c) * INNER + (kf >> 1) * 64 + 8 * g;
    bf16x8 a0 = ld_bf8(kp);
    bf16x8 a1 = ld_bf8(kp + 32);
    acc[0][kf] = __builtin_amdgcn_mfma_f32_16x16x32_bf16(a0, qfr[0][0], acc[0][kf], 0, 0, 0);
    acc[0][kf] = __builtin_amdgcn_mfma_f32_16x16x32_bf16(a1, qfr[0][1], acc[0][kf], 0, 0, 0);
    acc[1][kf] = __builtin_amdgcn_mfma_f32_16x16x32_bf16(a0, qfr[1][0], acc[1][kf], 0, 0, 0);
    acc[1][kf] = __builtin_amdgcn_mfma_f32_16x16x32_bf16(a1, qfr[1][1], acc[1][kf], 0, 0, 0);
  }

  // ---- softmax (normalization deferred) + P pack/write by key' ----
  float inv[2];
#pragma unroll
  for (int qf = 0; qf < 2; ++qf) {
    float m = acc[qf][0][0];
#pragma unroll
    for (int kf = 0; kf < 16; ++kf)
      m = fmaxf(m, fmaxf(fmaxf(acc[qf][kf][0], acc[qf][kf][1]),
                         fmaxf(acc[qf][kf][2], acc[qf][kf][3])));
    m = fmaxf(m, __shfl_xor(m, 16));
    m = fmaxf(m, __shfl_xor(m, 32));
    float sum = 0.f;
    const int q = 16 * qf + c;
    const int rowb = q * 512;                // 256 ushort per row
#pragma unroll
    for (int kf = 0; kf < 16; ++kf) {
      float e0 = __expf(acc[qf][kf][0] - m);
      float e1 = __expf(acc[qf][kf][1] - m);
      float e2 = __expf(acc[qf][kf][2] - m);
      float e3 = __expf(acc[qf][kf][3] - m);
      sum += (e0 + e1) + (e2 + e3);
      uint2 w;
      w.x = f2bf(e0) | (f2bf(e1) << 16);
      w.y = f2bf(e2) | (f2bf(e3) << 16);
      int off = (rowb + (16 * kf + 4 * g) * 2) ^ ((q & 7) << 4);
      *(uint2*)(Pb + off) = w;
    }
    sum += __shfl_xor(sum, 16);
    sum += __shfl_xor(sum, 32);
    inv[qf] = 1.f / sum;
  }
  asm volatile("" ::: "memory");  // keep P writes before P reads

  // ---- O^T = V^T · P : o[qf][cf], rows=channels, cols=queries ----
  f32x4 o[2][4];
#pragma unroll
  for (int qf = 0; qf < 2; ++qf)
#pragma unroll
    for (int cf = 0; cf < 4; ++cf) o[qf][cf] = (f32x4)0.f;
#pragma unroll
  for (int ks = 0; ks < 8; ++ks) {
    const int koff = (32 * ks + 8 * g) * 2;
    bf16x8 p0 = __builtin_bit_cast(bf16x8,
        *(const uint4*)(Pb + ((c * 512 + koff) ^ ((c & 7) << 4))));
    bf16x8 p1 = __builtin_bit_cast(bf16x8,
        *(const uint4*)(Pb + (((16 + c) * 512 + koff) ^ ((c & 7) << 4))));
#pragma unroll
    for (int cf = 0; cf < 4; ++cf) {
      bf16x8 a = ld_bf8(Vg + (size_t)(16 * cf + c) * MTOK + 32 * ks + 8 * g);
      o[0][cf] = __builtin_amdgcn_mfma_f32_16x16x32_bf16(a, p0, o[0][cf], 0, 0, 0);
      o[1][cf] = __builtin_amdgcn_mfma_f32_16x16x32_bf16(a, p1, o[1][cf], 0, 0, 0);
    }
  }

  // ---- normalize + store (channels contiguous per lane -> float4) ----
#pragma unroll
  for (int qf = 0; qf < 2; ++qf)
#pragma unroll
    for (int cf = 0; cf < 4; ++cf) {
      f32x4 r = o[qf][cf] * inv[qf];
      size_t row = (size_t)b * LROWS + qbase + 16 * qf + c;
      float* op = out2 + row * INNER + hh * CH + 16 * cf + 4 * g;
      *(f32x4*)op = r;
    }
}

// ---------------------------------------------------------------------------
// Kernel C: O = out2 @ Wo + bo (4096x512x64), then y row (b, L*8+r) =
// x row + O row (broadcast 8x). fp32.
// ---------------------------------------------------------------------------
__global__ __launch_bounds__(256) void proj_kernel(
    const float* __restrict__ out2,
    const float* __restrict__ Wo, const float* __restrict__ bo,
    const float* __restrict__ x, float* __restrict__ y) {
  __shared__ __align__(16) float As[32][68];
  __shared__ __align__(16) float Bs[32][68];
  const int t  = threadIdx.x;
  const int m0 = blockIdx.x * 64;            // 64 blocks over M=4096
  const int tx = t & 15, ty = t >> 4;
  float acc[4][4] = {};
  for (int k0 = 0; k0 < INNER; k0 += 32) {
#pragma unroll
    for (int j = 0; j < 8; ++j) {
      int idx = t + j * 256;
      As[idx & 31][idx >> 5] = out2[(size_t)(m0 + (idx >> 5)) * INNER + k0 + (idx & 31)];
    }
#pragma unroll
    for (int j = 0; j < 8; ++j) {
      int idx = t + j * 256;
      Bs[idx >> 6][idx & 63] = Wo[(size_t)(k0 + (idx >> 6)) * CH + (idx & 63)];
    }
    __syncthreads();
#pragma unroll
    for (int kk = 0; kk < 32; ++kk) {
      float a[4]; *(float4*)a = *(const float4*)&As[kk][ty * 4];
      float b[4]; *(float4*)b = *(const float4*)&Bs[kk][tx * 4];
#pragma unroll
      for (int i = 0; i < 4; ++i)
#pragma unroll
        for (int jj = 0; jj < 4; ++jj) acc[i][jj] += a[i] * b[jj];
    }
    __syncthreads();
  }
  float bo4[4]; *(float4*)bo4 = *(const float4*)&bo[tx * 4];
#pragma unroll
  for (int i = 0; i < 4; ++i) {
    int m = m0 + ty * 4 + i;
    int bb = m >> 9, L = m & 511;
    float4 val = make_float4(acc[i][0] + bo4[0], acc[i][1] + bo4[1],
                             acc[i][2] + bo4[2], acc[i][3] + bo4[3]);
    const float* xr = x + (size_t)bb * (HW * CH) + (size_t)L * 8 * CH + tx * 4;
    float*       yr = y + (size_t)bb * (HW * CH) + (size_t)L * 8 * CH + tx * 4;
#pragma unroll
    for (int r = 0; r < 8; ++r) {
      float xv[4]; *(float4*)xv = *(const float4*)&xr[r * CH];
      float4 ov = make_float4(val.x + xv[0], val.y + xv[1], val.z + xv[2], val.w + xv[3]);
      *(float4*)&yr[r * CH] = ov;
    }
  }
}

extern "C" void kernel_launch(void* const* d_in, const int* in_sizes, int n_in,
                              void* d_out, int out_size, void* d_ws, size_t ws_size,
                              hipStream_t stream) {
  const float* x  = (const float*)d_in[0];
  const float* z  = (const float*)d_in[1];
  const float* Wk = (const float*)d_in[2];
  const float* bk = (const float*)d_in[3];
  const float* Wv = (const float*)d_in[4];
  const float* bv = (const float*)d_in[5];
  const float* Wo = (const float*)d_in[6];
  const float* bo = (const float*)d_in[7];
  float* y = (float*)d_out;

  // ws: klin bf16 (2 MB) | vt bf16 (2 MB) | out2 f32 (8 MB)
  unsigned short* klin = (unsigned short*)d_ws;
  unsigned short* vt   = klin + (size_t)2048 * 512;
  float*          out2 = (float*)(vt + (size_t)2048 * 512);

  dim3 gA(32, 16);
  kv_gemm<<<gA, 256, 0, stream>>>(z, Wk, bk, Wv, bv, klin, vt);
  attn_mfma<<<1024, 64, 0, stream>>>(x, klin, vt, out2);
  proj_kernel<<<64, 256, 0, stream>>>(out2, Wo, bo, x, y);
}

// Round 5
// 47.027 us; speedup vs baseline: 2.3747x; 1.9393x over previous
//
#include <hip/hip_runtime.h>

#define HEADS 8
#define CH    64      // per-head dim == x channel dim
#define HW    4096
#define MTOK  256     // z tokens
#define DIMZ  256     // z feature dim
#define INNER 512     // heads*CH
#define LROWS 512     // HW/8 distinct query rows per head

typedef __attribute__((ext_vector_type(8))) __bf16 bf16x8;
typedef __attribute__((ext_vector_type(4))) float  f32x4;

// round-to-nearest-even f32 -> bf16 bits
__device__ __forceinline__ unsigned f2bf(float f) {
  unsigned u = __float_as_uint(f);
  return (u + 0x7fffu + ((u >> 16) & 1u)) >> 16;
}

__device__ __forceinline__ bf16x8 ld_bf8(const unsigned short* p) {
  uint4 v = *(const uint4*)p;
  return __builtin_bit_cast(bf16x8, v);
}

// ---------------------------------------------------------------------------
// Kernel 0 (prep): zbf = bf16(z) row-major (2048x256);
//   WkT/WvT = bf16(W^T) (512x256, k-contiguous); WoT = bf16(Wo^T) (64x512).
// ---------------------------------------------------------------------------
__global__ __launch_bounds__(256) void prep(
    const float* __restrict__ z, const float* __restrict__ Wk,
    const float* __restrict__ Wv, const float* __restrict__ Wo,
    unsigned short* __restrict__ zbf, unsigned short* __restrict__ WkT,
    unsigned short* __restrict__ WvT, unsigned short* __restrict__ WoT) {
  const int blk = blockIdx.x, tid = threadIdx.x;
  if (blk < 512) {                       // z: 2048*256 = 131072 float4
    int i = (blk * 256 + tid) * 4;
    float4 f = *(const float4*)(z + i);
    uint2 w;
    w.x = f2bf(f.x) | (f2bf(f.y) << 16);
    w.y = f2bf(f.z) | (f2bf(f.w) << 16);
    *(uint2*)(zbf + i) = w;
  } else if (blk < 768) {                // WkT / WvT: 512 n x 64 k-quads
    const bool isK = blk < 640;
    const float* __restrict__ W = isK ? Wk : Wv;
    unsigned short* __restrict__ WT = isK ? WkT : WvT;
    int gidx = (blk - (isK ? 512 : 640)) * 256 + tid;   // 0..32767
    int n = gidx >> 6, k0 = (gidx & 63) * 4;
    uint2 w;
    w.x = f2bf(W[(size_t)k0 * INNER + n])       | (f2bf(W[(size_t)(k0 + 1) * INNER + n]) << 16);
    w.y = f2bf(W[(size_t)(k0 + 2) * INNER + n]) | (f2bf(W[(size_t)(k0 + 3) * INNER + n]) << 16);
    *(uint2*)(WT + (size_t)n * DIMZ + k0) = w;
  } else {                               // WoT: 64 n x 128 k-quads
    int gidx = (blk - 768) * 256 + tid;  // 0..8191
    int n = gidx >> 7, k0 = (gidx & 127) * 4;
    uint2 w;
    w.x = f2bf(Wo[(size_t)k0 * CH + n])       | (f2bf(Wo[(size_t)(k0 + 1) * CH + n]) << 16);
    w.y = f2bf(Wo[(size_t)(k0 + 2) * CH + n]) | (f2bf(Wo[(size_t)(k0 + 3) * CH + n]) << 16);
    *(uint2*)(WoT + (size_t)n * INNER + k0) = w;
  }
}

// ---------------------------------------------------------------------------
// Kernel A (MFMA): klin = bf16(z@Wk + bk) row-major (2048x512);
//                  vt   = bf16(z@Wv + bv) in [b][h][c][key'], key' = cb*32+t.
// 512 blocks x 4 waves; 32x32 output tile per wave; fragments from global.
// K-branch: mfma(W,z) -> reg dim = n (pack 4n into klin rows).
// V-branch: mfma(z,W) -> reg dim = m (pack 4 tokens into vt).
// ---------------------------------------------------------------------------
__global__ __launch_bounds__(256) void kv_mfma(
    const unsigned short* __restrict__ zbf,
    const unsigned short* __restrict__ WkT, const float* __restrict__ bk,
    const unsigned short* __restrict__ WvT, const float* __restrict__ bv,
    unsigned short* __restrict__ klin, unsigned short* __restrict__ vt) {
  const int t = threadIdx.x;
  const int lane = t & 63, wid = t >> 6;
  const int c = lane & 15, g = lane >> 4;
  const int mb = blockIdx.x;                 // 0..31
  const int bn = blockIdx.y;                 // 0..15
  const bool isK = bn < 8;
  const int nb = bn & 7;
  const unsigned short* __restrict__ WT = isK ? WkT : WvT;
  const float* __restrict__ bias = isK ? bk : bv;
  const int m0 = mb * 64 + (wid >> 1) * 32;
  const int n0 = nb * 64 + (wid & 1) * 32;

  f32x4 acc[2][2];
#pragma unroll
  for (int i = 0; i < 2; ++i)
#pragma unroll
    for (int j = 0; j < 2; ++j) acc[i][j] = (f32x4)0.f;

#pragma unroll
  for (int s = 0; s < 8; ++s) {
    const int k0 = s * 32;
    bf16x8 a0 = ld_bf8(zbf + (size_t)(m0 + c) * DIMZ + k0 + 8 * g);
    bf16x8 a1 = ld_bf8(zbf + (size_t)(m0 + 16 + c) * DIMZ + k0 + 8 * g);
    bf16x8 b0 = ld_bf8(WT + (size_t)(n0 + c) * DIMZ + k0 + 8 * g);
    bf16x8 b1 = ld_bf8(WT + (size_t)(n0 + 16 + c) * DIMZ + k0 + 8 * g);
    if (isK) {   // D[n][m]
      acc[0][0] = __builtin_amdgcn_mfma_f32_16x16x32_bf16(b0, a0, acc[0][0], 0, 0, 0);
      acc[0][1] = __builtin_amdgcn_mfma_f32_16x16x32_bf16(b1, a0, acc[0][1], 0, 0, 0);
      acc[1][0] = __builtin_amdgcn_mfma_f32_16x16x32_bf16(b0, a1, acc[1][0], 0, 0, 0);
      acc[1][1] = __builtin_amdgcn_mfma_f32_16x16x32_bf16(b1, a1, acc[1][1], 0, 0, 0);
    } else {     // D[m][n]
      acc[0][0] = __builtin_amdgcn_mfma_f32_16x16x32_bf16(a0, b0, acc[0][0], 0, 0, 0);
      acc[0][1] = __builtin_amdgcn_mfma_f32_16x16x32_bf16(a0, b1, acc[0][1], 0, 0, 0);
      acc[1][0] = __builtin_amdgcn_mfma_f32_16x16x32_bf16(a1, b0, acc[1][0], 0, 0, 0);
      acc[1][1] = __builtin_amdgcn_mfma_f32_16x16x32_bf16(a1, b1, acc[1][1], 0, 0, 0);
    }
  }

  if (isK) {
    // acc[mt][nt]: rows n = n0+nt*16+4g+r, col m = m0+mt*16+c
#pragma unroll
    for (int mt = 0; mt < 2; ++mt)
#pragma unroll
      for (int nt = 0; nt < 2; ++nt) {
        const int m = m0 + mt * 16 + c;
        const int n = n0 + nt * 16 + 4 * g;
        float4 b4 = *(const float4*)(bias + n);
        uint2 w;
        w.x = f2bf(acc[mt][nt][0] + b4.x) | (f2bf(acc[mt][nt][1] + b4.y) << 16);
        w.y = f2bf(acc[mt][nt][2] + b4.z) | (f2bf(acc[mt][nt][3] + b4.w) << 16);
        *(uint2*)(klin + (size_t)m * INNER + n) = w;
      }
  } else {
    // acc[mt][nt]: rows m = m0+mt*16+4g+r (tokens), col n = n0+nt*16+c
#pragma unroll
    for (int mt = 0; mt < 2; ++mt)
#pragma unroll
      for (int nt = 0; nt < 2; ++nt) {
        const int n = n0 + nt * 16 + c;
        const float bn1 = bias[n];
        const int m = m0 + mt * 16 + 4 * g;
        const int bb = m >> 8;
        const int mtk = m & 255;
        const int h = mtk >> 5, t0 = mtk & 31;
        const int cc = n & 63, cb = n >> 6;
        uint2 w;
        w.x = f2bf(acc[mt][nt][0] + bn1) | (f2bf(acc[mt][nt][1] + bn1) << 16);
        w.y = f2bf(acc[mt][nt][2] + bn1) | (f2bf(acc[mt][nt][3] + bn1) << 16);
        *(uint2*)(vt + ((size_t)((bb * HEADS + h) * CH + cc)) * MTOK + cb * 32 + t0) = w;
      }
  }
}

// ---------------------------------------------------------------------------
// Kernel B (MFMA attention): one wave per (b, h, 32-query tile). Unchanged
// math from R4 (validated); epilogue now stores bf16 out2.
// ---------------------------------------------------------------------------
__global__ __launch_bounds__(64) void attn_mfma(
    const float* __restrict__ x,
    const unsigned short* __restrict__ kbf,
    const unsigned short* __restrict__ vtbf,
    unsigned short* __restrict__ out2) {
  __shared__ unsigned short Psh[32 * 256];   // 16 KB
  char* Pb = (char*)Psh;
  const int t = threadIdx.x;
  const int c = t & 15, g = t >> 4;
  const int bid = blockIdx.x;                // b*128 + hh*16 + lt
  const int lt = bid & 15, hh = (bid >> 4) & 7, b = bid >> 7;
  const int qbase = lt * 32;
  const float* xs = x + (size_t)b * (HW * CH) + (size_t)hh * (LROWS * CH);
  const unsigned short* Kg = kbf + ((size_t)b * MTOK + hh * 32) * INNER; // [32 tok][512]
  const unsigned short* Vg = vtbf + (size_t)(b * HEADS + hh) * (CH * MTOK);

  // ---- Q fragments (B-operand), scale 1/8 folded in (exact pow2) ----
  bf16x8 qfr[2][2];
#pragma unroll
  for (int qf = 0; qf < 2; ++qf)
#pragma unroll
    for (int ks = 0; ks < 2; ++ks) {
      const float* qp = xs + (size_t)(qbase + 16 * qf + c) * CH + 32 * ks + 8 * g;
      float4 f0 = *(const float4*)qp;
      float4 f1 = *(const float4*)(qp + 4);
      uint4 u;
      u.x = f2bf(f0.x * 0.125f) | (f2bf(f0.y * 0.125f) << 16);
      u.y = f2bf(f0.z * 0.125f) | (f2bf(f0.w * 0.125f) << 16);
      u.z = f2bf(f1.x * 0.125f) | (f2bf(f1.y * 0.125f) << 16);
      u.w = f2bf(f1.z * 0.125f) | (f2bf(f1.w * 0.125f) << 16);
      qfr[qf][ks] = __builtin_bit_cast(bf16x8, u);
    }

  // ---- S^T = K · Q^T : acc[qf][kf]; key' = 16*kf + (4g+r) ----
  f32x4 acc[2][16];
#pragma unroll
  for (int qf = 0; qf < 2; ++qf)
#pragma unroll
    for (int kf = 0; kf < 16; ++kf) acc[qf][kf] = (f32x4)0.f;
#pragma unroll
  for (int kf = 0; kf < 16; ++kf) {
    const unsigned short* kp =
        Kg + (size_t)((kf & 1) * 16 + c) * INNER + (kf >> 1) * 64 + 8 * g;
    bf16x8 a0 = ld_bf8(kp);
    bf16x8 a1 = ld_bf8(kp + 32);
    acc[0][kf] = __builtin_amdgcn_mfma_f32_16x16x32_bf16(a0, qfr[0][0], acc[0][kf], 0, 0, 0);
    acc[0][kf] = __builtin_amdgcn_mfma_f32_16x16x32_bf16(a1, qfr[0][1], acc[0][kf], 0, 0, 0);
    acc[1][kf] = __builtin_amdgcn_mfma_f32_16x16x32_bf16(a0, qfr[1][0], acc[1][kf], 0, 0, 0);
    acc[1][kf] = __builtin_amdgcn_mfma_f32_16x16x32_bf16(a1, qfr[1][1], acc[1][kf], 0, 0, 0);
  }

  // ---- softmax (normalization deferred) + P pack/write by key' ----
  float inv[2];
#pragma unroll
  for (int qf = 0; qf < 2; ++qf) {
    float m = acc[qf][0][0];
#pragma unroll
    for (int kf = 0; kf < 16; ++kf)
      m = fmaxf(m, fmaxf(fmaxf(acc[qf][kf][0], acc[qf][kf][1]),
                         fmaxf(acc[qf][kf][2], acc[qf][kf][3])));
    m = fmaxf(m, __shfl_xor(m, 16));
    m = fmaxf(m, __shfl_xor(m, 32));
    float sum = 0.f;
    const int q = 16 * qf + c;
    const int rowb = q * 512;                // 256 ushort per row
#pragma unroll
    for (int kf = 0; kf < 16; ++kf) {
      float e0 = __expf(acc[qf][kf][0] - m);
      float e1 = __expf(acc[qf][kf][1] - m);
      float e2 = __expf(acc[qf][kf][2] - m);
      float e3 = __expf(acc[qf][kf][3] - m);
      sum += (e0 + e1) + (e2 + e3);
      uint2 w;
      w.x = f2bf(e0) | (f2bf(e1) << 16);
      w.y = f2bf(e2) | (f2bf(e3) << 16);
      int off = (rowb + (16 * kf + 4 * g) * 2) ^ ((q & 7) << 4);
      *(uint2*)(Pb + off) = w;
    }
    sum += __shfl_xor(sum, 16);
    sum += __shfl_xor(sum, 32);
    inv[qf] = 1.f / sum;
  }
  asm volatile("" ::: "memory");  // keep P writes before P reads

  // ---- O^T = V^T · P : o[qf][cf], rows=channels, cols=queries ----
  f32x4 o[2][4];
#pragma unroll
  for (int qf = 0; qf < 2; ++qf)
#pragma unroll
    for (int cf = 0; cf < 4; ++cf) o[qf][cf] = (f32x4)0.f;
#pragma unroll
  for (int ks = 0; ks < 8; ++ks) {
    const int koff = (32 * ks + 8 * g) * 2;
    bf16x8 p0 = __builtin_bit_cast(bf16x8,
        *(const uint4*)(Pb + ((c * 512 + koff) ^ ((c & 7) << 4))));
    bf16x8 p1 = __builtin_bit_cast(bf16x8,
        *(const uint4*)(Pb + (((16 + c) * 512 + koff) ^ ((c & 7) << 4))));
#pragma unroll
    for (int cf = 0; cf < 4; ++cf) {
      bf16x8 a = ld_bf8(Vg + (size_t)(16 * cf + c) * MTOK + 32 * ks + 8 * g);
      o[0][cf] = __builtin_amdgcn_mfma_f32_16x16x32_bf16(a, p0, o[0][cf], 0, 0, 0);
      o[1][cf] = __builtin_amdgcn_mfma_f32_16x16x32_bf16(a, p1, o[1][cf], 0, 0, 0);
    }
  }

  // ---- normalize + store bf16 (channels contiguous per lane) ----
#pragma unroll
  for (int qf = 0; qf < 2; ++qf)
#pragma unroll
    for (int cf = 0; cf < 4; ++cf) {
      f32x4 r = o[qf][cf] * inv[qf];
      size_t row = (size_t)b * LROWS + qbase + 16 * qf + c;
      uint2 w;
      w.x = f2bf(r[0]) | (f2bf(r[1]) << 16);
      w.y = f2bf(r[2]) | (f2bf(r[3]) << 16);
      *(uint2*)(out2 + row * INNER + hh * CH + 16 * cf + 4 * g) = w;
    }
}

// ---------------------------------------------------------------------------
// Kernel C (MFMA proj): O = out2 @ Wo + bo (4096x512x64), K split over 4
// waves (128 each), LDS reduce, then y[b, L*8+r] = x + O (broadcast 8x).
// ---------------------------------------------------------------------------
__global__ __launch_bounds__(256) void proj_mfma(
    const unsigned short* __restrict__ out2,
    const unsigned short* __restrict__ WoT, const float* __restrict__ bo,
    const float* __restrict__ x, float* __restrict__ y) {
  __shared__ __align__(16) float Sp[4][16][68];
  const int t = threadIdx.x, lane = t & 63, wid = t >> 6;
  const int c = lane & 15, g = lane >> 4;
  const int m0 = blockIdx.x * 16;            // 256 blocks over M=4096
  const int kw = wid * 128;

  f32x4 acc[4];
#pragma unroll
  for (int nt = 0; nt < 4; ++nt) acc[nt] = (f32x4)0.f;
#pragma unroll
  for (int s = 0; s < 4; ++s) {
    const int k0 = kw + s * 32;
    bf16x8 bfr = ld_bf8(out2 + (size_t)(m0 + c) * INNER + k0 + 8 * g);
#pragma unroll
    for (int nt = 0; nt < 4; ++nt) {
      bf16x8 afr = ld_bf8(WoT + (size_t)(nt * 16 + c) * INNER + k0 + 8 * g);
      acc[nt] = __builtin_amdgcn_mfma_f32_16x16x32_bf16(afr, bfr, acc[nt], 0, 0, 0);
    }
  }
  // D rows n = nt*16+4g+r, col m-idx = c  ->  Sp[wid][c][n]
#pragma unroll
  for (int nt = 0; nt < 4; ++nt)
    *(f32x4*)&Sp[wid][c][nt * 16 + 4 * g] = acc[nt];
  __syncthreads();

  const int i = t >> 4, j0 = (t & 15) * 4;
  float4 s0 = *(const float4*)&Sp[0][i][j0];
  float4 s1 = *(const float4*)&Sp[1][i][j0];
  float4 s2 = *(const float4*)&Sp[2][i][j0];
  float4 s3 = *(const float4*)&Sp[3][i][j0];
  float4 b4 = *(const float4*)(bo + j0);
  float4 o4 = make_float4(s0.x + s1.x + s2.x + s3.x + b4.x,
                          s0.y + s1.y + s2.y + s3.y + b4.y,
                          s0.z + s1.z + s2.z + s3.z + b4.z,
                          s0.w + s1.w + s2.w + s3.w + b4.w);
  const int m = m0 + i, bb = m >> 9, L = m & 511;
  const float* xr = x + (size_t)bb * (HW * CH) + (size_t)L * 8 * CH + j0;
  float*       yr = y + (size_t)bb * (HW * CH) + (size_t)L * 8 * CH + j0;
#pragma unroll
  for (int r = 0; r < 8; ++r) {
    float4 xv = *(const float4*)(xr + r * CH);
    float4 ov = make_float4(o4.x + xv.x, o4.y + xv.y, o4.z + xv.z, o4.w + xv.w);
    *(float4*)(yr + r * CH) = ov;
  }
}

extern "C" void kernel_launch(void* const* d_in, const int* in_sizes, int n_in,
                              void* d_out, int out_size, void* d_ws, size_t ws_size,
                              hipStream_t stream) {
  const float* x  = (const float*)d_in[0];
  const float* z  = (const float*)d_in[1];
  const float* Wk = (const float*)d_in[2];
  const float* bk = (const float*)d_in[3];
  const float* Wv = (const float*)d_in[4];
  const float* bv = (const float*)d_in[5];
  const float* Wo = (const float*)d_in[6];
  const float* bo = (const float*)d_in[7];
  float* y = (float*)d_out;

  // ws layout (ushort units): zbf 512K | WkT 128K | WvT 128K | WoT 32K |
  //                           klin 1M | vt 1M | out2 2M   (~10 MB total)
  unsigned short* zbf  = (unsigned short*)d_ws;
  unsigned short* WkT  = zbf  + (size_t)2048 * DIMZ;
  unsigned short* WvT  = WkT  + (size_t)INNER * DIMZ;
  unsigned short* WoT  = WvT  + (size_t)INNER * DIMZ;
  unsigned short* klin = WoT  + (size_t)CH * INNER;
  unsigned short* vt   = klin + (size_t)2048 * INNER;
  unsigned short* out2 = vt   + (size_t)2048 * INNER;

  prep<<<800, 256, 0, stream>>>(z, Wk, Wv, Wo, zbf, WkT, WvT, WoT);
  dim3 gA(32, 16);
  kv_mfma<<<gA, 256, 0, stream>>>(zbf, WkT, bk, WvT, bv, klin, vt);
  attn_mfma<<<1024, 64, 0, stream>>>(x, klin, vt, out2);
  proj_mfma<<<256, 256, 0, stream>>>(out2, WoT, bo, x, y);
}